// Round 1
// baseline (1039.991 us; speedup 1.0000x reference)
//
#include <hip/hip_runtime.h>
#include <math.h>

// ---------------- conv1: (B,1,64,64) -> (B,4,32,32), k5 s2 p2, ReLU ----------------
__global__ void conv1_kernel(const float* __restrict__ x, const float* __restrict__ w,
                             const float* __restrict__ bias, float* __restrict__ out) {
    __shared__ float sw[100];
    __shared__ float sb[4];
    int tid = threadIdx.x;
    if (tid < 100) sw[tid] = w[tid];
    if (tid < 4) sb[tid] = bias[tid];
    __syncthreads();
    int idx = blockIdx.x * 256 + tid;          // 4096*4*32*32 = 16777216
    int ow = idx & 31;
    int oh = (idx >> 5) & 31;
    int oc = (idx >> 10) & 3;
    int b  = idx >> 12;
    const float* xin = x + b * 4096;
    const float* wk = sw + oc * 25;
    float acc = sb[oc];
    int ih0 = oh * 2 - 2;
    int iw0 = ow * 2 - 2;
    #pragma unroll
    for (int kh = 0; kh < 5; kh++) {
        int ih = ih0 + kh;
        if (ih < 0 || ih >= 64) continue;
        #pragma unroll
        for (int kw = 0; kw < 5; kw++) {
            int iw = iw0 + kw;
            if (iw < 0 || iw >= 64) continue;
            acc = fmaf(xin[ih * 64 + iw], wk[kh * 5 + kw], acc);
        }
    }
    out[idx] = fmaxf(acc, 0.0f);
}

// ---------------- conv2: (B,4,32,32) -> (B,8,16,16), k3 s2 p1, ReLU ----------------
__global__ void conv2_kernel(const float* __restrict__ in, const float* __restrict__ w,
                             const float* __restrict__ bias, float* __restrict__ out) {
    __shared__ float sw[288];
    __shared__ float sb[8];
    int tid = threadIdx.x;
    for (int i = tid; i < 288; i += 256) sw[i] = w[i];
    if (tid < 8) sb[tid] = bias[tid];
    __syncthreads();
    int idx = blockIdx.x * 256 + tid;          // 4096*8*16*16 = 8388608
    int ow = idx & 15;
    int oh = (idx >> 4) & 15;
    int oc = (idx >> 8) & 7;
    int b  = idx >> 11;
    const float* xin = in + b * 4 * 1024;
    float acc = sb[oc];
    int ih0 = oh * 2 - 1;
    int iw0 = ow * 2 - 1;
    for (int ic = 0; ic < 4; ic++) {
        const float* xc = xin + ic * 1024;
        const float* wk = sw + (oc * 4 + ic) * 9;
        #pragma unroll
        for (int kh = 0; kh < 3; kh++) {
            int ih = ih0 + kh;
            if (ih < 0 || ih >= 32) continue;
            #pragma unroll
            for (int kw = 0; kw < 3; kw++) {
                int iw = iw0 + kw;
                if (iw < 0 || iw >= 32) continue;
                acc = fmaf(xc[ih * 32 + iw], wk[kh * 3 + kw], acc);
            }
        }
    }
    out[idx] = fmaxf(acc, 0.0f);
}

// ---------------- conv3: (B,8,16,16) -> (B,16,16,16), k3 s1 p1, ReLU ----------------
__global__ void conv3_kernel(const float* __restrict__ in, const float* __restrict__ w,
                             const float* __restrict__ bias, float* __restrict__ out) {
    __shared__ float sw[1152];
    __shared__ float sb[16];
    int tid = threadIdx.x;
    for (int i = tid; i < 1152; i += 256) sw[i] = w[i];
    if (tid < 16) sb[tid] = bias[tid];
    __syncthreads();
    int idx = blockIdx.x * 256 + tid;          // 4096*16*16*16 = 16777216
    int ow = idx & 15;
    int oh = (idx >> 4) & 15;
    int oc = (idx >> 8) & 15;
    int b  = idx >> 12;
    const float* xin = in + b * 8 * 256;
    float acc = sb[oc];
    for (int ic = 0; ic < 8; ic++) {
        const float* xc = xin + ic * 256;
        const float* wk = sw + (oc * 8 + ic) * 9;
        #pragma unroll
        for (int kh = 0; kh < 3; kh++) {
            int ih = oh - 1 + kh;
            if (ih < 0 || ih >= 16) continue;
            #pragma unroll
            for (int kw = 0; kw < 3; kw++) {
                int iw = ow - 1 + kw;
                if (iw < 0 || iw >= 16) continue;
                acc = fmaf(xc[ih * 16 + iw], wk[kh * 3 + kw], acc);
            }
        }
    }
    out[idx] = fmaxf(acc, 0.0f);
}

// ---------------- head: pool + fc + normalize + quantum + MLP + sigmoid ----------------
// one block (256 threads) per batch element; statevector (256 fp32) in LDS
__global__ void head_kernel(const float* __restrict__ conv3out,
                            const float* __restrict__ wf, const float* __restrict__ bf,
                            const float* __restrict__ qw,
                            const float* __restrict__ wc1, const float* __restrict__ bc1,
                            const float* __restrict__ wc2, const float* __restrict__ bc2,
                            const float* __restrict__ wc3, const float* __restrict__ bc3,
                            const float* __restrict__ wc4, const float* __restrict__ bc4,
                            const float* __restrict__ wc5, const float* __restrict__ bc5,
                            float* __restrict__ out) {
    __shared__ float pool[64];
    __shared__ float psi[256];
    __shared__ float cs_c[56], cs_s[56];
    __shared__ float red[4];
    __shared__ float h1[200], h2[150], h3[100], h4[50];
    __shared__ float sbc0;   // broadcast scalar (inv-norm, then z)
    int tid = threadIdx.x;
    int b = blockIdx.x;
    int lane = tid & 63;
    int wave = tid >> 6;

    // rotation angles: theta/2 -> cos, sin
    if (tid < 56) {
        float th = qw[tid] * 0.5f;
        cs_c[tid] = cosf(th);
        cs_s[tid] = sinf(th);
    }
    // 8x8 average pool: (16,16,16) -> 64 values
    if (tid < 64) {
        int ch = tid >> 2, i = (tid >> 1) & 1, j = tid & 1;
        const float* p = conv3out + b * 4096 + ch * 256 + (i * 8) * 16 + j * 8;
        float s = 0.0f;
        #pragma unroll
        for (int hh = 0; hh < 8; hh++)
            #pragma unroll
            for (int ww = 0; ww < 8; ww++)
                s += p[hh * 16 + ww];
        pool[tid] = s * (1.0f / 64.0f);
    }
    __syncthreads();

    // fc: feats[tid] = relu(dot64(pool, wf_row) + bf)
    {
        const float* wrow = wf + tid * 64;
        float acc = bf[tid];
        #pragma unroll
        for (int k = 0; k < 64; k++) acc = fmaf(pool[k], wrow[k], acc);
        psi[tid] = fmaxf(acc, 0.0f);
    }
    __syncthreads();

    // L2 normalize (ref normalizes twice; mathematically identical for nonzero)
    float v = psi[tid];
    float ss = v * v;
    #pragma unroll
    for (int off = 32; off > 0; off >>= 1) ss += __shfl_down(ss, off, 64);
    if (lane == 0) red[wave] = ss;
    __syncthreads();
    if (tid == 0) {
        float tot = red[0] + red[1] + red[2] + red[3];
        sbc0 = 1.0f / fmaxf(sqrtf(tot), 1e-12f);
    }
    __syncthreads();
    psi[tid] = v * sbc0;

    // quantum circuit: 7 layers of (RY on each qubit, then CNOT chain)
    // qubit q <-> bit (7-q) of the amplitude index
    for (int l = 0; l < 7; l++) {
        #pragma unroll
        for (int q = 0; q < 8; q++) {
            int bit = 1 << (7 - q);
            float c = cs_c[l * 8 + q];
            float s = cs_s[l * 8 + q];
            __syncthreads();
            if ((tid & bit) == 0) {
                float a0 = psi[tid];
                float a1 = psi[tid | bit];
                psi[tid]       = c * a0 - s * a1;
                psi[tid | bit] = s * a0 + c * a1;
            }
        }
        #pragma unroll
        for (int q = 0; q < 7; q++) {
            int cb = 1 << (7 - q);
            int tb = 1 << (6 - q);
            __syncthreads();
            if ((tid & cb) && !(tid & tb)) {
                float a0 = psi[tid];
                float a1 = psi[tid | tb];
                psi[tid]      = a1;
                psi[tid | tb] = a0;
            }
        }
    }
    __syncthreads();

    // <Z_0>: sum(psi^2 for idx<128) - sum(psi^2 for idx>=128)
    float a = psi[tid];
    float m = a * a;
    if (tid >= 128) m = -m;
    #pragma unroll
    for (int off = 32; off > 0; off >>= 1) m += __shfl_down(m, off, 64);
    if (lane == 0) red[wave] = m;
    __syncthreads();
    if (tid == 0) sbc0 = red[0] + red[1] + red[2] + red[3];
    __syncthreads();
    float z = sbc0;

    // classifier MLP
    if (tid < 200) h1[tid] = fmaxf(fmaf(z, wc1[tid], bc1[tid]), 0.0f);
    __syncthreads();
    if (tid < 150) {
        const float* wr = wc2 + tid * 200;
        float acc = bc2[tid];
        for (int k = 0; k < 200; k++) acc = fmaf(wr[k], h1[k], acc);
        h2[tid] = fmaxf(acc, 0.0f);
    }
    __syncthreads();
    if (tid < 100) {
        const float* wr = wc3 + tid * 150;
        float acc = bc3[tid];
        for (int k = 0; k < 150; k++) acc = fmaf(wr[k], h2[k], acc);
        h3[tid] = fmaxf(acc, 0.0f);
    }
    __syncthreads();
    if (tid < 50) {
        const float* wr = wc4 + tid * 100;
        float acc = bc4[tid];
        for (int k = 0; k < 100; k++) acc = fmaf(wr[k], h3[k], acc);
        h4[tid] = fmaxf(acc, 0.0f);
    }
    __syncthreads();
    if (tid == 0) {
        float acc = bc5[0];
        for (int k = 0; k < 50; k++) acc = fmaf(wc5[k], h4[k], acc);
        out[b] = 1.0f / (1.0f + expf(-acc));
    }
}

extern "C" void kernel_launch(void* const* d_in, const int* in_sizes, int n_in,
                              void* d_out, int out_size, void* d_ws, size_t ws_size,
                              hipStream_t stream) {
    const float* x   = (const float*)d_in[0];
    const float* w1  = (const float*)d_in[1];
    const float* b1  = (const float*)d_in[2];
    const float* w2  = (const float*)d_in[3];
    const float* b2  = (const float*)d_in[4];
    const float* w3  = (const float*)d_in[5];
    const float* b3  = (const float*)d_in[6];
    const float* wf  = (const float*)d_in[7];
    const float* bf  = (const float*)d_in[8];
    const float* qw  = (const float*)d_in[9];
    const float* wc1 = (const float*)d_in[10];
    const float* bc1 = (const float*)d_in[11];
    const float* wc2 = (const float*)d_in[12];
    const float* bc2 = (const float*)d_in[13];
    const float* wc3 = (const float*)d_in[14];
    const float* bc3 = (const float*)d_in[15];
    const float* wc4 = (const float*)d_in[16];
    const float* bc4 = (const float*)d_in[17];
    const float* wc5 = (const float*)d_in[18];
    const float* bc5 = (const float*)d_in[19];
    float* out = (float*)d_out;

    // workspace ping-pong: A (16.7M floats) | B (8.4M floats) -> 100.7 MB total
    float* bufA = (float*)d_ws;
    float* bufB = bufA + 16777216;

    conv1_kernel<<<65536, 256, 0, stream>>>(x,    w1, b1, bufA);
    conv2_kernel<<<32768, 256, 0, stream>>>(bufA, w2, b2, bufB);
    conv3_kernel<<<65536, 256, 0, stream>>>(bufB, w3, b3, bufA);
    head_kernel<<<4096, 256, 0, stream>>>(bufA, wf, bf, qw,
                                          wc1, bc1, wc2, bc2, wc3, bc3,
                                          wc4, bc4, wc5, bc5, out);
}

// Round 2
// 544.081 us; speedup vs baseline: 1.9115x; 1.9115x over previous
//
#include <hip/hip_runtime.h>
#include <math.h>

// Fully fused CNN+QNN: one block (256 threads) per batch element.
// LDS layouts (padded strides chosen for low bank aliasing):
//   regA[4160]: x as 64x65  ->  conv2-out as [8][16][18] (2304) + head scratch
//   regB[4368]: conv1-out as [4][32][33] (4224) -> conv3-out as [16][16][17] ch-stride 273
//   w3s[1168］: w3 (1152) + b3 (16)
__global__ __launch_bounds__(256, 3)
void fused_kernel(const float* __restrict__ x,
                  const float* __restrict__ w1, const float* __restrict__ b1,
                  const float* __restrict__ w2, const float* __restrict__ b2,
                  const float* __restrict__ w3, const float* __restrict__ b3,
                  const float* __restrict__ wf, const float* __restrict__ bf,
                  const float* __restrict__ qw,
                  const float* __restrict__ wc1, const float* __restrict__ bc1,
                  const float* __restrict__ wc2, const float* __restrict__ bc2,
                  const float* __restrict__ wc3, const float* __restrict__ bc3,
                  const float* __restrict__ wc4, const float* __restrict__ bc4,
                  const float* __restrict__ wc5, const float* __restrict__ bc5,
                  float* __restrict__ out)
{
    __shared__ __align__(16) float regA[4160];
    __shared__ __align__(16) float regB[4368];
    __shared__ __align__(16) float w3s[1168];

    // head scratch inside regA (x dead after conv1; conv2-out occupies [0,2304))
    float* pool = regA + 2304;   // 64
    float* psiL = regA + 2368;   // 256
    float* h1   = regA + 2624;   // 200
    float* h2   = regA + 2824;   // 150
    float* h3   = regA + 2974;   // 100
    float* h4   = regA + 3074;   // 50
    float* zs   = regA + 3124;   // 1
    float* csc  = regA + 3136;   // 56
    float* css  = regA + 3192;   // 56

    const int tid  = threadIdx.x;
    const int b    = blockIdx.x;
    const int lane = tid & 63;

    // ---- stage x (64x64 -> LDS 64x65) + w3/b3 -> LDS ----
    {
        const float4* xv = (const float4*)(x + (size_t)b * 4096);
        #pragma unroll
        for (int j = 0; j < 4; j++) {
            int idx4 = j * 256 + tid;            // float4 index
            float4 v = xv[idx4];
            int row = idx4 >> 4;
            int c4  = (idx4 & 15) * 4;
            float* p = regA + row * 65 + c4;
            p[0] = v.x; p[1] = v.y; p[2] = v.z; p[3] = v.w;
        }
        for (int i = tid; i < 1168; i += 256) w3s[i] = (i < 1152) ? w3[i] : b3[i - 1152];
    }
    __syncthreads();

    // ---- conv1: x(64x65) -> regB [4][32][33], k5 s2 p2, ReLU ----
    // thread handles 4 consecutive ow per group; oc compile-time uniform -> scalar weights
    #pragma unroll
    for (int i = 0; i < 4; i++) {
        const int oc  = i;
        const int oh  = tid >> 3;
        const int ow0 = (tid & 7) * 4;
        float a0 = b1[oc], a1 = a0, a2 = a0, a3 = a0;
        const int c0 = ow0 * 2 - 2;
        #pragma unroll
        for (int kh = 0; kh < 5; kh++) {
            const int ih = oh * 2 - 2 + kh;
            if (ih < 0 || ih >= 64) continue;
            float colv[11];
            #pragma unroll
            for (int cc = 0; cc < 11; cc++) {
                const int c = c0 + cc;
                colv[cc] = (c >= 0 && c < 64) ? regA[ih * 65 + c] : 0.0f;
            }
            #pragma unroll
            for (int kw = 0; kw < 5; kw++) {
                const float wv = w1[oc * 25 + kh * 5 + kw];
                a0 = fmaf(colv[0 + kw], wv, a0);
                a1 = fmaf(colv[2 + kw], wv, a1);
                a2 = fmaf(colv[4 + kw], wv, a2);
                a3 = fmaf(colv[6 + kw], wv, a3);
            }
        }
        float* o = regB + oc * 1056 + oh * 33 + ow0;
        o[0] = fmaxf(a0, 0.f); o[1] = fmaxf(a1, 0.f);
        o[2] = fmaxf(a2, 0.f); o[3] = fmaxf(a3, 0.f);
    }
    __syncthreads();

    // ---- conv2: regB [4][32][33] -> regA [8][16][18], k3 s2 p1, ReLU ----
    if (tid < 56) {  // rotation angles (area overlaps dead x region only)
        float th = qw[tid] * 0.5f;
        csc[tid] = cosf(th);
        css[tid] = sinf(th);
    }
    #pragma unroll
    for (int i = 0; i < 2; i++) {
        const int g   = i * 256 + tid;
        const int oc  = __builtin_amdgcn_readfirstlane(g >> 6);  // wave-uniform
        const int oh  = lane >> 2;
        const int ow0 = (lane & 3) * 4;
        float a0 = b2[oc], a1 = a0, a2 = a0, a3 = a0;
        const int c0 = ow0 * 2 - 1;
        #pragma unroll
        for (int ic = 0; ic < 4; ic++) {
            const float* xc = regB + ic * 1056;
            const float* wk = w2 + (oc * 4 + ic) * 9;
            #pragma unroll
            for (int kh = 0; kh < 3; kh++) {
                const int ih = oh * 2 - 1 + kh;
                if (ih < 0 || ih >= 32) continue;
                float colv[9];
                #pragma unroll
                for (int cc = 0; cc < 9; cc++) {
                    const int c = c0 + cc;
                    colv[cc] = (c >= 0 && c < 32) ? xc[ih * 33 + c] : 0.0f;
                }
                #pragma unroll
                for (int kw = 0; kw < 3; kw++) {
                    const float wv = wk[kh * 3 + kw];
                    a0 = fmaf(colv[0 + kw], wv, a0);
                    a1 = fmaf(colv[2 + kw], wv, a1);
                    a2 = fmaf(colv[4 + kw], wv, a2);
                    a3 = fmaf(colv[6 + kw], wv, a3);
                }
            }
        }
        float* o = regA + oc * 288 + oh * 18 + ow0;
        o[0] = fmaxf(a0, 0.f); o[1] = fmaxf(a1, 0.f);
        o[2] = fmaxf(a2, 0.f); o[3] = fmaxf(a3, 0.f);
    }
    __syncthreads();

    // ---- conv3: regA [8][16][18] -> regB [16][16][17] (ch stride 273), k3 s1 p1 ----
    // thread = (oc, 4x4 spatial tile); weights from LDS (divergent oc)
    {
        const int oc = tid >> 4;
        const int s  = tid & 15;
        const int tr = (s >> 2) * 4;
        const int tc = (s & 3) * 4;
        float acc[16];
        const float bv = w3s[1152 + oc];
        #pragma unroll
        for (int k = 0; k < 16; k++) acc[k] = bv;
        #pragma unroll
        for (int ic = 0; ic < 8; ic++) {
            const float* xc = regA + ic * 288;
            float p[6][6];
            #pragma unroll
            for (int dr = 0; dr < 6; dr++) {
                const int ir = tr - 1 + dr;
                #pragma unroll
                for (int dc = 0; dc < 6; dc++) {
                    const int jc = tc - 1 + dc;
                    p[dr][dc] = (ir >= 0 && ir < 16 && jc >= 0 && jc < 16)
                              ? xc[ir * 18 + jc] : 0.0f;
                }
            }
            float wv[9];
            #pragma unroll
            for (int k = 0; k < 9; k++) wv[k] = w3s[oc * 72 + ic * 9 + k];
            #pragma unroll
            for (int r = 0; r < 4; r++)
                #pragma unroll
                for (int c = 0; c < 4; c++) {
                    float a = acc[r * 4 + c];
                    #pragma unroll
                    for (int kh = 0; kh < 3; kh++)
                        #pragma unroll
                        for (int kw = 0; kw < 3; kw++)
                            a = fmaf(p[r + kh][c + kw], wv[kh * 3 + kw], a);
                    acc[r * 4 + c] = a;
                }
        }
        float* o = regB + oc * 273;
        #pragma unroll
        for (int r = 0; r < 4; r++)
            #pragma unroll
            for (int c = 0; c < 4; c++)
                o[(tr + r) * 17 + tc + c] = fmaxf(acc[r * 4 + c], 0.f);
    }
    __syncthreads();

    // ---- 8x8 average pool: regB [16][16][17] -> pool[64] ----
    if (tid < 64) {
        const int ch = tid >> 2, ii = (tid >> 1) & 1, jj = tid & 1;
        const float* p = regB + ch * 273 + (ii * 8) * 17 + jj * 8;
        float ssum = 0.f;
        #pragma unroll
        for (int hh = 0; hh < 8; hh++)
            #pragma unroll
            for (int ww = 0; ww < 8; ww++) ssum += p[hh * 17 + ww];
        pool[tid] = ssum * (1.f / 64.f);
    }
    __syncthreads();

    // ---- fc: feats[tid] = relu(dot64(pool, wf row) + bf) ----
    {
        const float4* wr = (const float4*)(wf + tid * 64);
        const float4* pl = (const float4*)pool;
        float acc = bf[tid];
        #pragma unroll
        for (int k = 0; k < 16; k++) {
            float4 a = wr[k], p4 = pl[k];
            acc = fmaf(a.x, p4.x, acc); acc = fmaf(a.y, p4.y, acc);
            acc = fmaf(a.z, p4.z, acc); acc = fmaf(a.w, p4.w, acc);
        }
        psiL[tid] = fmaxf(acc, 0.f);
    }
    __syncthreads();

    // ---- quantum circuit: wave 0 only, 4 amplitudes/lane, shfl_xor, no barriers ----
    // amp index = j*64 + lane; qubit q <-> bit p = 7-q (p=7 -> j bit1, p=6 -> j bit0)
    if (tid < 64) {
        float v0 = psiL[lane], v1 = psiL[64 + lane];
        float v2 = psiL[128 + lane], v3 = psiL[192 + lane];
        float ssq = v0 * v0 + v1 * v1 + v2 * v2 + v3 * v3;
        #pragma unroll
        for (int off = 1; off < 64; off <<= 1) ssq += __shfl_xor(ssq, off, 64);
        const float inv = 1.0f / fmaxf(sqrtf(ssq), 1e-12f);
        v0 *= inv; v1 *= inv; v2 *= inv; v3 *= inv;

        for (int l = 0; l < 7; l++) {
            {   // RY q=0 (p=7): pairs (v0,v2),(v1,v3)
                float c = csc[l * 8 + 0], s = css[l * 8 + 0];
                float n0 = c * v0 - s * v2, n2 = s * v0 + c * v2;
                float n1 = c * v1 - s * v3, n3 = s * v1 + c * v3;
                v0 = n0; v1 = n1; v2 = n2; v3 = n3;
            }
            {   // RY q=1 (p=6): pairs (v0,v1),(v2,v3)
                float c = csc[l * 8 + 1], s = css[l * 8 + 1];
                float n0 = c * v0 - s * v1, n1 = s * v0 + c * v1;
                float n2 = c * v2 - s * v3, n3 = s * v2 + c * v3;
                v0 = n0; v1 = n1; v2 = n2; v3 = n3;
            }
            #pragma unroll
            for (int q = 2; q < 8; q++) {   // RY on lane bits p=5..0
                const int p = 7 - q;
                const int m = 1 << p;
                float c = csc[l * 8 + q], s = css[l * 8 + q];
                float sgn = (lane & m) ? s : -s;
                float t0 = __shfl_xor(v0, m, 64);
                float t1 = __shfl_xor(v1, m, 64);
                float t2 = __shfl_xor(v2, m, 64);
                float t3 = __shfl_xor(v3, m, 64);
                v0 = fmaf(sgn, t0, c * v0);
                v1 = fmaf(sgn, t1, c * v1);
                v2 = fmaf(sgn, t2, c * v2);
                v3 = fmaf(sgn, t3, c * v3);
            }
            // CNOT chain q=0..6 (control pc=7-q, target pt=6-q)
            { float t = v2; v2 = v3; v3 = t; }            // q=0: j=2 <-> j=3
            v1 = __shfl_xor(v1, 32, 64);                  // q=1: j-bit0 set -> flip lane bit5
            v3 = __shfl_xor(v3, 32, 64);
            #pragma unroll
            for (int q = 2; q < 7; q++) {                 // lane-bit control+target
                const int mc = 1 << (7 - q), mt = 1 << (6 - q);
                float t0 = __shfl_xor(v0, mt, 64);
                float t1 = __shfl_xor(v1, mt, 64);
                float t2 = __shfl_xor(v2, mt, 64);
                float t3 = __shfl_xor(v3, mt, 64);
                if (lane & mc) { v0 = t0; v1 = t1; v2 = t2; v3 = t3; }
            }
        }
        float m0 = v0 * v0 + v1 * v1 - v2 * v2 - v3 * v3;  // <Z0>: bit7 = j bit1
        #pragma unroll
        for (int off = 1; off < 64; off <<= 1) m0 += __shfl_xor(m0, off, 64);
        if (lane == 0) zs[0] = m0;
    }
    __syncthreads();

    // ---- classifier MLP ----
    const float z = zs[0];
    if (tid < 200) h1[tid] = fmaxf(fmaf(z, wc1[tid], bc1[tid]), 0.f);
    __syncthreads();
    if (tid < 150) {
        const float4* wr = (const float4*)(wc2 + tid * 200);
        float acc = bc2[tid];
        #pragma unroll 10
        for (int k = 0; k < 50; k++) {
            float4 a = wr[k];
            acc = fmaf(a.x, h1[k * 4 + 0], acc); acc = fmaf(a.y, h1[k * 4 + 1], acc);
            acc = fmaf(a.z, h1[k * 4 + 2], acc); acc = fmaf(a.w, h1[k * 4 + 3], acc);
        }
        h2[tid] = fmaxf(acc, 0.f);
    }
    __syncthreads();
    if (tid < 100) {
        const float2* wr = (const float2*)(wc3 + tid * 150);
        float acc = bc3[tid];
        #pragma unroll 15
        for (int k = 0; k < 75; k++) {
            float2 a = wr[k];
            acc = fmaf(a.x, h2[k * 2 + 0], acc); acc = fmaf(a.y, h2[k * 2 + 1], acc);
        }
        h3[tid] = fmaxf(acc, 0.f);
    }
    __syncthreads();
    if (tid < 50) {
        const float4* wr = (const float4*)(wc4 + tid * 100);
        float acc = bc4[tid];
        #pragma unroll
        for (int k = 0; k < 25; k++) {
            float4 a = wr[k];
            acc = fmaf(a.x, h3[k * 4 + 0], acc); acc = fmaf(a.y, h3[k * 4 + 1], acc);
            acc = fmaf(a.z, h3[k * 4 + 2], acc); acc = fmaf(a.w, h3[k * 4 + 3], acc);
        }
        h4[tid] = fmaxf(acc, 0.f);
    }
    __syncthreads();
    if (tid == 0) {
        float acc = bc5[0];
        #pragma unroll
        for (int k = 0; k < 25; k++) {
            float2 a = ((const float2*)wc5)[k];
            acc = fmaf(a.x, h4[k * 2 + 0], acc); acc = fmaf(a.y, h4[k * 2 + 1], acc);
        }
        out[b] = 1.0f / (1.0f + expf(-acc));
    }
}

extern "C" void kernel_launch(void* const* d_in, const int* in_sizes, int n_in,
                              void* d_out, int out_size, void* d_ws, size_t ws_size,
                              hipStream_t stream) {
    const float* x   = (const float*)d_in[0];
    const float* w1  = (const float*)d_in[1];
    const float* b1  = (const float*)d_in[2];
    const float* w2  = (const float*)d_in[3];
    const float* b2  = (const float*)d_in[4];
    const float* w3  = (const float*)d_in[5];
    const float* b3  = (const float*)d_in[6];
    const float* wf  = (const float*)d_in[7];
    const float* bf  = (const float*)d_in[8];
    const float* qw  = (const float*)d_in[9];
    const float* wc1 = (const float*)d_in[10];
    const float* bc1 = (const float*)d_in[11];
    const float* wc2 = (const float*)d_in[12];
    const float* bc2 = (const float*)d_in[13];
    const float* wc3 = (const float*)d_in[14];
    const float* bc3 = (const float*)d_in[15];
    const float* wc4 = (const float*)d_in[16];
    const float* bc4 = (const float*)d_in[17];
    const float* wc5 = (const float*)d_in[18];
    const float* bc5 = (const float*)d_in[19];
    float* out = (float*)d_out;

    fused_kernel<<<4096, 256, 0, stream>>>(x, w1, b1, w2, b2, w3, b3, wf, bf, qw,
                                           wc1, bc1, wc2, bc2, wc3, bc3,
                                           wc4, bc4, wc5, bc5, out);
}

// Round 3
// 234.376 us; speedup vs baseline: 4.4373x; 2.3214x over previous
//
#include <hip/hip_runtime.h>
#include <math.h>

// ================= Kernel A: conv1+conv2+conv3+pool, one block per element =================
// LDS arenas:
//  regA[4160]: x as 64x65  ->  conv2-out halo [8][18][18] (2592)
//  regB[4620]: conv1-out halo [4][33][35]  ->  conv3-out [16] ch-stride 273, row-stride 17
//  w3s[1168]:  w3 (1152) + b3 (16)
__global__ __launch_bounds__(256, 4)
void convpool_kernel(const float* __restrict__ x,
                     const float* __restrict__ w1, const float* __restrict__ b1,
                     const float* __restrict__ w2, const float* __restrict__ b2,
                     const float* __restrict__ w3, const float* __restrict__ b3,
                     float* __restrict__ poolout)
{
    __shared__ __align__(16) float regA[4160];
    __shared__ __align__(16) float regB[4620];
    __shared__ __align__(16) float w3s[1168];
    const int tid = threadIdx.x;
    const int b   = blockIdx.x;

    // ---- stage x (64x64 -> 64x65) + w3/b3 + zero conv1-out halo ----
    {
        const float4* xv = (const float4*)(x + (size_t)b * 4096);
        #pragma unroll
        for (int j = 0; j < 4; j++) {
            int i4 = j * 256 + tid;
            float4 v = xv[i4];
            int r = i4 >> 4, c = (i4 & 15) * 4;
            float* p = regA + r * 65 + c;
            p[0] = v.x; p[1] = v.y; p[2] = v.z; p[3] = v.w;
        }
        for (int i = tid; i < 1168; i += 256) w3s[i] = (i < 1152) ? w3[i] : b3[i - 1152];
        // conv1-out halo: stored row 0 (35 cols) + stored col 0 (33 rows), per oc
        for (int i = tid; i < 140; i += 256) { int oc = i / 35, c = i - oc * 35; regB[oc * 1155 + c] = 0.f; }
        for (int i = tid; i < 132; i += 256) { int oc = i / 33, r = i - oc * 33; regB[oc * 1155 + r * 35] = 0.f; }
    }
    __syncthreads();

    // ---- conv1: k5 s2 p2, 4 oc accumulated per colv read ----
    {
        const int oh = tid >> 3, ow0 = (tid & 7) * 4;
        float acc[4][4];
        #pragma unroll
        for (int oc = 0; oc < 4; oc++) {
            const float bv = b1[oc];
            #pragma unroll
            for (int j = 0; j < 4; j++) acc[oc][j] = bv;
        }
        const int c0 = ow0 * 2 - 2;
        #pragma unroll
        for (int kh = 0; kh < 5; kh++) {
            const int ih = oh * 2 - 2 + kh;
            const bool rv = (ih >= 0) && (ih < 64);
            float colv[11];
            #pragma unroll
            for (int cc = 0; cc < 11; cc++) {
                const int c = c0 + cc;
                colv[cc] = (rv && c >= 0 && c < 64) ? regA[ih * 65 + c] : 0.f;
            }
            #pragma unroll
            for (int kw = 0; kw < 5; kw++) {
                #pragma unroll
                for (int oc = 0; oc < 4; oc++) {
                    const float wv = w1[oc * 25 + kh * 5 + kw];
                    acc[oc][0] = fmaf(colv[0 + kw], wv, acc[oc][0]);
                    acc[oc][1] = fmaf(colv[2 + kw], wv, acc[oc][1]);
                    acc[oc][2] = fmaf(colv[4 + kw], wv, acc[oc][2]);
                    acc[oc][3] = fmaf(colv[6 + kw], wv, acc[oc][3]);
                }
            }
        }
        #pragma unroll
        for (int oc = 0; oc < 4; oc++) {
            float* o = regB + oc * 1155 + (oh + 1) * 35 + ow0 + 1;
            #pragma unroll
            for (int j = 0; j < 4; j++) o[j] = fmaxf(acc[oc][j], 0.f);
        }
    }
    __syncthreads();

    // ---- zero conv2-out halo (x dead) + conv2: k3 s2 p1, 2 oc per colv read ----
    for (int i = tid; i < 576; i += 256) {
        const int ch = i / 72, j = i - ch * 72;
        if (j < 18)      regA[ch * 324 + j] = 0.f;                   // stored row 0
        else if (j < 36) regA[ch * 324 + 17 * 18 + (j - 18)] = 0.f;  // stored row 17
        else if (j < 52) regA[ch * 324 + (j - 35) * 18] = 0.f;       // stored col 0, rows 1..16
        else if (j < 68) regA[ch * 324 + (j - 51) * 18 + 17] = 0.f;  // stored col 17, rows 1..16
    }
    {
        const int lane = tid & 63;
        const int oc0  = __builtin_amdgcn_readfirstlane(tid >> 6);   // wave-uniform
        const int oh = lane >> 2, ow0 = (lane & 3) * 4;
        float acc[2][4];
        {
            const float ba = b2[oc0], bb = b2[oc0 + 4];
            #pragma unroll
            for (int j = 0; j < 4; j++) { acc[0][j] = ba; acc[1][j] = bb; }
        }
        const int c0s = ow0 * 2;            // stored col base (logical -1 -> stored 0)
        #pragma unroll
        for (int ic = 0; ic < 4; ic++) {
            const float* base = regB + ic * 1155;
            #pragma unroll
            for (int kh = 0; kh < 3; kh++) {
                const int ihs = oh * 2 + kh;  // stored row, always in [0,32]
                float colv[9];
                #pragma unroll
                for (int cc = 0; cc < 9; cc++) colv[cc] = base[ihs * 35 + c0s + cc];
                #pragma unroll
                for (int kw = 0; kw < 3; kw++) {
                    const float wa = w2[((oc0    ) * 4 + ic) * 9 + kh * 3 + kw];
                    const float wb = w2[((oc0 + 4) * 4 + ic) * 9 + kh * 3 + kw];
                    #pragma unroll
                    for (int j = 0; j < 4; j++) {
                        acc[0][j] = fmaf(colv[2 * j + kw], wa, acc[0][j]);
                        acc[1][j] = fmaf(colv[2 * j + kw], wb, acc[1][j]);
                    }
                }
            }
        }
        float* oA = regA + oc0 * 324       + (oh + 1) * 18 + ow0 + 1;
        float* oB = regA + (oc0 + 4) * 324 + (oh + 1) * 18 + ow0 + 1;
        #pragma unroll
        for (int j = 0; j < 4; j++) { oA[j] = fmaxf(acc[0][j], 0.f); oB[j] = fmaxf(acc[1][j], 0.f); }
    }
    __syncthreads();

    // ---- conv3: [8][18][18] halo -> regB ch-stride 273, no guards ----
    {
        const int oc = tid >> 4, s = tid & 15;
        const int tr = (s >> 2) * 4, tc = (s & 3) * 4;
        float acc[16];
        const float bv = w3s[1152 + oc];
        #pragma unroll
        for (int k = 0; k < 16; k++) acc[k] = bv;
        #pragma unroll
        for (int ic = 0; ic < 8; ic++) {
            const float* xc = regA + ic * 324;
            float p[6][6];
            #pragma unroll
            for (int dr = 0; dr < 6; dr++)
                #pragma unroll
                for (int dc = 0; dc < 6; dc++)
                    p[dr][dc] = xc[(tr + dr) * 18 + (tc + dc)];
            float wv[9];
            #pragma unroll
            for (int k = 0; k < 9; k++) wv[k] = w3s[oc * 72 + ic * 9 + k];
            #pragma unroll
            for (int r = 0; r < 4; r++)
                #pragma unroll
                for (int c = 0; c < 4; c++) {
                    float a = acc[r * 4 + c];
                    #pragma unroll
                    for (int kh = 0; kh < 3; kh++)
                        #pragma unroll
                        for (int kw = 0; kw < 3; kw++)
                            a = fmaf(p[r + kh][c + kw], wv[kh * 3 + kw], a);
                    acc[r * 4 + c] = a;
                }
        }
        float* o = regB + oc * 273;
        #pragma unroll
        for (int r = 0; r < 4; r++)
            #pragma unroll
            for (int c = 0; c < 4; c++)
                o[(tr + r) * 17 + tc + c] = fmaxf(acc[r * 4 + c], 0.f);
    }
    __syncthreads();

    // ---- 8x8 average pool -> global (4096 x 64) ----
    if (tid < 64) {
        const int ch = tid >> 2, ii = (tid >> 1) & 1, jj = tid & 1;
        const float* p = regB + ch * 273 + (ii * 8) * 17 + jj * 8;
        float s = 0.f;
        #pragma unroll
        for (int hh = 0; hh < 8; hh++)
            #pragma unroll
            for (int ww = 0; ww < 8; ww++) s += p[hh * 17 + ww];
        poolout[b * 64 + tid] = s * (1.f / 64.f);
    }
}

// ================= Kernel B: fc + normalize + quantum + MLP, 8 elements per block =================
__global__ __launch_bounds__(256)
void head_kernel(const float* __restrict__ poolin,
                 const float* __restrict__ wf, const float* __restrict__ bf,
                 const float* __restrict__ qw,
                 const float* __restrict__ wc1, const float* __restrict__ bc1,
                 const float* __restrict__ wc2, const float* __restrict__ bc2,
                 const float* __restrict__ wc3, const float* __restrict__ bc3,
                 const float* __restrict__ wc4, const float* __restrict__ bc4,
                 const float* __restrict__ wc5, const float* __restrict__ bc5,
                 float* __restrict__ out)
{
    __shared__ __align__(16) float pool_s[512];    // [8][64]
    __shared__ __align__(16) float feats[2048];    // [8][256]
    __shared__ __align__(16) float h1[1600];       // [8][200]
    __shared__ __align__(16) float h2[1200];       // [8][150]
    __shared__ __align__(16) float h3[800];        // [8][100]
    __shared__ __align__(16) float h4[400];        // [8][50]
    __shared__ float zbuf[8];
    __shared__ float csc[56], css[56];

    const int tid  = threadIdx.x;
    const int blk  = blockIdx.x;
    const int lane = tid & 63;
    const int wv   = tid >> 6;

    // stage pool rows (8x64 contiguous) + angles
    ((float2*)pool_s)[tid] = ((const float2*)(poolin + (size_t)blk * 512))[tid];
    if (tid < 56) {
        float th = qw[tid] * 0.5f;
        csc[tid] = cosf(th);
        css[tid] = sinf(th);
    }
    __syncthreads();

    // ---- fc: thread t owns feature o=t for all 8 elements (weight row reused 8x) ----
    {
        float acc[8];
        const float bv = bf[tid];
        #pragma unroll
        for (int e = 0; e < 8; e++) acc[e] = bv;
        const float4* wr = (const float4*)(wf + tid * 64);
        #pragma unroll
        for (int kc = 0; kc < 4; kc++) {
            float4 w0 = wr[kc * 4 + 0], w1_ = wr[kc * 4 + 1], w2_ = wr[kc * 4 + 2], w3_ = wr[kc * 4 + 3];
            #pragma unroll
            for (int e = 0; e < 8; e++) {
                const float4* pp = (const float4*)(pool_s + e * 64 + kc * 16);
                float4 p0 = pp[0], p1 = pp[1], p2 = pp[2], p3 = pp[3];
                float a = acc[e];
                a = fmaf(w0.x, p0.x, a); a = fmaf(w0.y, p0.y, a); a = fmaf(w0.z, p0.z, a); a = fmaf(w0.w, p0.w, a);
                a = fmaf(w1_.x, p1.x, a); a = fmaf(w1_.y, p1.y, a); a = fmaf(w1_.z, p1.z, a); a = fmaf(w1_.w, p1.w, a);
                a = fmaf(w2_.x, p2.x, a); a = fmaf(w2_.y, p2.y, a); a = fmaf(w2_.z, p2.z, a); a = fmaf(w2_.w, p2.w, a);
                a = fmaf(w3_.x, p3.x, a); a = fmaf(w3_.y, p3.y, a); a = fmaf(w3_.z, p3.z, a); a = fmaf(w3_.w, p3.w, a);
                acc[e] = a;
            }
        }
        #pragma unroll
        for (int e = 0; e < 8; e++) feats[e * 256 + tid] = fmaxf(acc[e], 0.f);
    }
    __syncthreads();

    // ---- quantum: each wave runs 2 elements with ILP; amp idx = j*64 + lane ----
    {
        float v[2][4];
        #pragma unroll
        for (int u = 0; u < 2; u++) {
            const float* base = feats + (wv * 2 + u) * 256;
            v[u][0] = base[lane]; v[u][1] = base[64 + lane];
            v[u][2] = base[128 + lane]; v[u][3] = base[192 + lane];
        }
        float ssq[2];
        #pragma unroll
        for (int u = 0; u < 2; u++)
            ssq[u] = v[u][0]*v[u][0] + v[u][1]*v[u][1] + v[u][2]*v[u][2] + v[u][3]*v[u][3];
        #pragma unroll
        for (int off = 1; off < 64; off <<= 1) {
            ssq[0] += __shfl_xor(ssq[0], off, 64);
            ssq[1] += __shfl_xor(ssq[1], off, 64);
        }
        #pragma unroll
        for (int u = 0; u < 2; u++) {
            const float inv = 1.0f / fmaxf(sqrtf(ssq[u]), 1e-12f);
            v[u][0] *= inv; v[u][1] *= inv; v[u][2] *= inv; v[u][3] *= inv;
        }

        for (int l = 0; l < 7; l++) {
            #pragma unroll
            for (int u = 0; u < 2; u++) {   // RY q=0 (j bit1), q=1 (j bit0)
                float c = csc[l * 8 + 0], s = css[l * 8 + 0];
                float n0 = c*v[u][0] - s*v[u][2], n2 = s*v[u][0] + c*v[u][2];
                float n1 = c*v[u][1] - s*v[u][3], n3 = s*v[u][1] + c*v[u][3];
                float c1 = csc[l * 8 + 1], s1 = css[l * 8 + 1];
                v[u][0] = c1*n0 - s1*n1; v[u][1] = s1*n0 + c1*n1;
                v[u][2] = c1*n2 - s1*n3; v[u][3] = s1*n2 + c1*n3;
            }
            #pragma unroll
            for (int q = 2; q < 8; q++) {   // RY on lane bits 5..0
                const int m = 1 << (7 - q);
                const float c = csc[l * 8 + q], s = css[l * 8 + q];
                const float sgn = (lane & m) ? s : -s;
                #pragma unroll
                for (int u = 0; u < 2; u++) {
                    float t0 = __shfl_xor(v[u][0], m, 64);
                    float t1 = __shfl_xor(v[u][1], m, 64);
                    float t2 = __shfl_xor(v[u][2], m, 64);
                    float t3 = __shfl_xor(v[u][3], m, 64);
                    v[u][0] = fmaf(sgn, t0, c * v[u][0]);
                    v[u][1] = fmaf(sgn, t1, c * v[u][1]);
                    v[u][2] = fmaf(sgn, t2, c * v[u][2]);
                    v[u][3] = fmaf(sgn, t3, c * v[u][3]);
                }
            }
            // CNOT chain
            #pragma unroll
            for (int u = 0; u < 2; u++) {
                float t = v[u][2]; v[u][2] = v[u][3]; v[u][3] = t;     // q=0
                v[u][1] = __shfl_xor(v[u][1], 32, 64);                 // q=1
                v[u][3] = __shfl_xor(v[u][3], 32, 64);
            }
            #pragma unroll
            for (int q = 2; q < 7; q++) {
                const int mc = 1 << (7 - q), mt = 1 << (6 - q);
                #pragma unroll
                for (int u = 0; u < 2; u++) {
                    float t0 = __shfl_xor(v[u][0], mt, 64);
                    float t1 = __shfl_xor(v[u][1], mt, 64);
                    float t2 = __shfl_xor(v[u][2], mt, 64);
                    float t3 = __shfl_xor(v[u][3], mt, 64);
                    if (lane & mc) { v[u][0] = t0; v[u][1] = t1; v[u][2] = t2; v[u][3] = t3; }
                }
            }
        }
        float m0[2];
        #pragma unroll
        for (int u = 0; u < 2; u++)
            m0[u] = v[u][0]*v[u][0] + v[u][1]*v[u][1] - v[u][2]*v[u][2] - v[u][3]*v[u][3];
        #pragma unroll
        for (int off = 1; off < 64; off <<= 1) {
            m0[0] += __shfl_xor(m0[0], off, 64);
            m0[1] += __shfl_xor(m0[1], off, 64);
        }
        if (lane == 0) { zbuf[wv * 2] = m0[0]; zbuf[wv * 2 + 1] = m0[1]; }
    }
    __syncthreads();

    // ---- MLP (weights in registers, reused across 8 elements; h reads broadcast) ----
    if (tid < 200) {
        const float w = wc1[tid], bv = bc1[tid];
        #pragma unroll
        for (int e = 0; e < 8; e++) h1[e * 200 + tid] = fmaxf(fmaf(zbuf[e], w, bv), 0.f);
    }
    __syncthreads();
    if (tid < 150) {
        float acc[8];
        const float bv = bc2[tid];
        #pragma unroll
        for (int e = 0; e < 8; e++) acc[e] = bv;
        const float4* wr = (const float4*)(wc2 + tid * 200);
        for (int kc = 0; kc < 25; kc++) {
            float4 wa = wr[2 * kc], wb = wr[2 * kc + 1];
            #pragma unroll
            for (int e = 0; e < 8; e++) {
                const float4* hp = (const float4*)(h1 + e * 200) + 2 * kc;
                float4 ha = hp[0], hb = hp[1];
                float a = acc[e];
                a = fmaf(wa.x, ha.x, a); a = fmaf(wa.y, ha.y, a); a = fmaf(wa.z, ha.z, a); a = fmaf(wa.w, ha.w, a);
                a = fmaf(wb.x, hb.x, a); a = fmaf(wb.y, hb.y, a); a = fmaf(wb.z, hb.z, a); a = fmaf(wb.w, hb.w, a);
                acc[e] = a;
            }
        }
        #pragma unroll
        for (int e = 0; e < 8; e++) h2[e * 150 + tid] = fmaxf(acc[e], 0.f);
    }
    __syncthreads();
    if (tid < 100) {
        float acc[8];
        const float bv = bc3[tid];
        #pragma unroll
        for (int e = 0; e < 8; e++) acc[e] = bv;
        const float2* wr = (const float2*)(wc3 + tid * 150);
        for (int k = 0; k < 75; k++) {
            float2 wa = wr[k];
            #pragma unroll
            for (int e = 0; e < 8; e++) {
                float2 hv = ((const float2*)(h2 + e * 150))[k];
                acc[e] = fmaf(wa.x, hv.x, fmaf(wa.y, hv.y, acc[e]));
            }
        }
        #pragma unroll
        for (int e = 0; e < 8; e++) h3[e * 100 + tid] = fmaxf(acc[e], 0.f);
    }
    __syncthreads();
    if (tid < 50) {
        float acc[8];
        const float bv = bc4[tid];
        #pragma unroll
        for (int e = 0; e < 8; e++) acc[e] = bv;
        const float4* wr = (const float4*)(wc4 + tid * 100);
        for (int kc = 0; kc < 25; kc++) {
            float4 wa = wr[kc];
            #pragma unroll
            for (int e = 0; e < 8; e++) {
                float4 hv = ((const float4*)(h3 + e * 100))[kc];
                float a = acc[e];
                a = fmaf(wa.x, hv.x, a); a = fmaf(wa.y, hv.y, a);
                a = fmaf(wa.z, hv.z, a); a = fmaf(wa.w, hv.w, a);
                acc[e] = a;
            }
        }
        #pragma unroll
        for (int e = 0; e < 8; e++) h4[e * 50 + tid] = fmaxf(acc[e], 0.f);
    }
    __syncthreads();
    if (tid < 8) {
        float acc = bc5[0];
        const float2* wr = (const float2*)wc5;
        #pragma unroll
        for (int k = 0; k < 25; k++) {
            float2 wa = wr[k];
            float2 hv = ((const float2*)(h4 + tid * 50))[k];
            acc = fmaf(wa.x, hv.x, fmaf(wa.y, hv.y, acc));
        }
        out[blk * 8 + tid] = 1.0f / (1.0f + expf(-acc));
    }
}

extern "C" void kernel_launch(void* const* d_in, const int* in_sizes, int n_in,
                              void* d_out, int out_size, void* d_ws, size_t ws_size,
                              hipStream_t stream) {
    const float* x   = (const float*)d_in[0];
    const float* w1  = (const float*)d_in[1];
    const float* b1  = (const float*)d_in[2];
    const float* w2  = (const float*)d_in[3];
    const float* b2  = (const float*)d_in[4];
    const float* w3  = (const float*)d_in[5];
    const float* b3  = (const float*)d_in[6];
    const float* wf  = (const float*)d_in[7];
    const float* bf  = (const float*)d_in[8];
    const float* qw  = (const float*)d_in[9];
    const float* wc1 = (const float*)d_in[10];
    const float* bc1 = (const float*)d_in[11];
    const float* wc2 = (const float*)d_in[12];
    const float* bc2 = (const float*)d_in[13];
    const float* wc3 = (const float*)d_in[14];
    const float* bc3 = (const float*)d_in[15];
    const float* wc4 = (const float*)d_in[16];
    const float* bc4 = (const float*)d_in[17];
    const float* wc5 = (const float*)d_in[18];
    const float* bc5 = (const float*)d_in[19];
    float* out = (float*)d_out;

    float* poolbuf = (float*)d_ws;   // 4096*64 floats = 1 MB

    convpool_kernel<<<4096, 256, 0, stream>>>(x, w1, b1, w2, b2, w3, b3, poolbuf);
    head_kernel<<<512, 256, 0, stream>>>(poolbuf, wf, bf, qw,
                                         wc1, bc1, wc2, bc2, wc3, bc3,
                                         wc4, bc4, wc5, bc5, out);
}

// Round 4
// 218.506 us; speedup vs baseline: 4.7596x; 1.0726x over previous
//
#include <hip/hip_runtime.h>
#include <math.h>

// ================= Kernel A: conv1+conv2+conv3+pool fused, one block per image =================
// LDS: arena[4620] holds conv1-out halo [4][33][35] then conv2-out halo [8][18][18] (2592).
//      w3s[1168] = w3 (1152) + b3 (16).  Peak 5788 floats = 23.2 KB -> 6 blocks/CU.
__global__ __launch_bounds__(256, 6)
void convpool_kernel(const float* __restrict__ x,
                     const float* __restrict__ w1, const float* __restrict__ b1,
                     const float* __restrict__ w2, const float* __restrict__ b2,
                     const float* __restrict__ w3, const float* __restrict__ b3,
                     float* __restrict__ poolout)
{
    __shared__ __align__(16) float arena[4620];
    __shared__ __align__(16) float w3s[1168];
    const int tid  = threadIdx.x;
    const int b    = blockIdx.x;
    const int lane = tid & 63;

    // ---- stage w3/b3; zero conv1-out halo (row 0 + col 0 per oc) ----
    for (int i = tid; i < 1168; i += 256) w3s[i] = (i < 1152) ? w3[i] : b3[i - 1152];
    for (int i = tid; i < 140; i += 256) { int oc = i / 35, c = i - oc * 35; arena[oc * 1155 + c] = 0.f; }
    for (int i = tid; i < 132; i += 256) { int oc = i / 33, r = i - oc * 33; arena[oc * 1155 + r * 35] = 0.f; }

    // ---- conv1: x from GLOBAL, k5 s2 p2, 4 oc x 4 px per thread, row guards via exec branch ----
    {
        const float* xb = x + (size_t)b * 4096;
        const int oh  = tid >> 3;
        const int ow  = tid & 7;
        const int ow0 = ow * 4;
        const int c0  = ow0 * 2 - 2;             // in {-2,6,14,...,54}
        const bool cmL = (ow == 0);              // c0, c0+1 out of range on the left
        const bool cmR = (ow == 7);              // c0+10 == 64 out of range on the right
        float acc[4][4];
        #pragma unroll
        for (int oc = 0; oc < 4; oc++) {
            const float bv = b1[oc];
            #pragma unroll
            for (int j = 0; j < 4; j++) acc[oc][j] = bv;
        }
        #pragma unroll
        for (int kh = 0; kh < 5; kh++) {
            const int ih = oh * 2 - 2 + kh;
            if (ih >= 0 && ih < 64) {            // lanes with invalid row skip loads+FMAs
                const float* row = xb + ih * 64;
                float colv[11];
                // edge-clamped addresses (always in-bounds), values masked to 0
                {
                    float v0 = row[cmL ? 0 : c0];
                    float v1 = row[cmL ? 0 : c0 + 1];
                    float vA = row[cmR ? 63 : c0 + 10];
                    colv[0]  = cmL ? 0.f : v0;
                    colv[1]  = cmL ? 0.f : v1;
                    colv[10] = cmR ? 0.f : vA;
                }
                #pragma unroll
                for (int cc = 2; cc < 10; cc++) colv[cc] = row[c0 + cc];
                #pragma unroll
                for (int kw = 0; kw < 5; kw++) {
                    #pragma unroll
                    for (int oc = 0; oc < 4; oc++) {
                        const float wv = w1[oc * 25 + kh * 5 + kw];
                        acc[oc][0] = fmaf(colv[0 + kw], wv, acc[oc][0]);
                        acc[oc][1] = fmaf(colv[2 + kw], wv, acc[oc][1]);
                        acc[oc][2] = fmaf(colv[4 + kw], wv, acc[oc][2]);
                        acc[oc][3] = fmaf(colv[6 + kw], wv, acc[oc][3]);
                    }
                }
            }
        }
        #pragma unroll
        for (int oc = 0; oc < 4; oc++) {
            float* o = arena + oc * 1155 + (oh + 1) * 35 + ow0 + 1;
            #pragma unroll
            for (int j = 0; j < 4; j++) o[j] = fmaxf(acc[oc][j], 0.f);
        }
    }
    __syncthreads();

    // ---- conv2: arena [4][33][35] -> registers, k3 s2 p1, 2 oc x 4 px per thread ----
    float r2[2][4];
    {
        const int oc0 = __builtin_amdgcn_readfirstlane(tid >> 6);   // wave-uniform
        const int oh  = lane >> 2, ow0 = (lane & 3) * 4;
        {
            const float ba = b2[oc0], bb = b2[oc0 + 4];
            #pragma unroll
            for (int j = 0; j < 4; j++) { r2[0][j] = ba; r2[1][j] = bb; }
        }
        const int c0s = ow0 * 2;                 // stored col base (logical -1 -> stored 0)
        #pragma unroll
        for (int ic = 0; ic < 4; ic++) {
            const float* base = arena + ic * 1155;
            #pragma unroll
            for (int kh = 0; kh < 3; kh++) {
                const int ihs = oh * 2 + kh;     // stored row, in [0,32]
                float colv[9];
                #pragma unroll
                for (int cc = 0; cc < 9; cc++) colv[cc] = base[ihs * 35 + c0s + cc];
                #pragma unroll
                for (int kw = 0; kw < 3; kw++) {
                    const float wa = w2[((oc0    ) * 4 + ic) * 9 + kh * 3 + kw];
                    const float wb = w2[((oc0 + 4) * 4 + ic) * 9 + kh * 3 + kw];
                    #pragma unroll
                    for (int j = 0; j < 4; j++) {
                        r2[0][j] = fmaf(colv[2 * j + kw], wa, r2[0][j]);
                        r2[1][j] = fmaf(colv[2 * j + kw], wb, r2[1][j]);
                    }
                }
            }
        }
    }
    __syncthreads();   // all conv1-out reads done; arena can be reused

    // ---- write conv2-out halo [8][18][18] into arena (overlay) ----
    for (int i = tid; i < 576; i += 256) {
        const int ch = i / 72, j = i - ch * 72;
        if (j < 18)      arena[ch * 324 + j] = 0.f;
        else if (j < 36) arena[ch * 324 + 17 * 18 + (j - 18)] = 0.f;
        else if (j < 52) arena[ch * 324 + (j - 35) * 18] = 0.f;
        else if (j < 68) arena[ch * 324 + (j - 51) * 18 + 17] = 0.f;
    }
    {
        const int oc0 = __builtin_amdgcn_readfirstlane(tid >> 6);
        const int oh  = lane >> 2, ow0 = (lane & 3) * 4;
        float* oA = arena + oc0 * 324       + (oh + 1) * 18 + ow0 + 1;
        float* oB = arena + (oc0 + 4) * 324 + (oh + 1) * 18 + ow0 + 1;
        #pragma unroll
        for (int j = 0; j < 4; j++) { oA[j] = fmaxf(r2[0][j], 0.f); oB[j] = fmaxf(r2[1][j], 0.f); }
    }
    __syncthreads();

    // ---- conv3 + fused 8x8 avg pool: each thread -> one 4x4 tile of one oc ----
    {
        const int oc = tid >> 4, s = tid & 15;
        const int tr = (s >> 2) * 4, tc = (s & 3) * 4;
        float acc[16];
        const float bv = w3s[1152 + oc];
        #pragma unroll
        for (int k = 0; k < 16; k++) acc[k] = bv;
        #pragma unroll
        for (int ic = 0; ic < 8; ic++) {
            const float* xc = arena + ic * 324;
            float p[6][6];
            #pragma unroll
            for (int dr = 0; dr < 6; dr++)
                #pragma unroll
                for (int dc = 0; dc < 6; dc++)
                    p[dr][dc] = xc[(tr + dr) * 18 + (tc + dc)];
            float wv[9];
            #pragma unroll
            for (int k = 0; k < 9; k++) wv[k] = w3s[oc * 72 + ic * 9 + k];
            #pragma unroll
            for (int r = 0; r < 4; r++)
                #pragma unroll
                for (int c = 0; c < 4; c++) {
                    float a = acc[r * 4 + c];
                    #pragma unroll
                    for (int kh = 0; kh < 3; kh++)
                        #pragma unroll
                        for (int kw = 0; kw < 3; kw++)
                            a = fmaf(p[r + kh][c + kw], wv[kh * 3 + kw], a);
                    acc[r * 4 + c] = a;
                }
        }
        // relu + tile sum, then reduce 4 tiles per 8x8 quadrant via shfl
        float ps = 0.f;
        #pragma unroll
        for (int k = 0; k < 16; k++) ps += fmaxf(acc[k], 0.f);
        ps += __shfl_xor(ps, 1, 64);   // tc 0<->4, 8<->12
        ps += __shfl_xor(ps, 4, 64);   // tr 0<->4, 8<->12
        if ((s & 5) == 0) {
            const int ii = s >> 3, jj = (s >> 1) & 1;
            poolout[b * 64 + oc * 4 + ii * 2 + jj] = ps * (1.f / 64.f);
        }
    }
}

// ================= Kernel B: fc + normalize + quantum + MLP, 4 elements per block =================
__global__ __launch_bounds__(256)
void head_kernel(const float* __restrict__ poolin,
                 const float* __restrict__ wf, const float* __restrict__ bf,
                 const float* __restrict__ qw,
                 const float* __restrict__ wc1, const float* __restrict__ bc1,
                 const float* __restrict__ wc2, const float* __restrict__ bc2,
                 const float* __restrict__ wc3, const float* __restrict__ bc3,
                 const float* __restrict__ wc4, const float* __restrict__ bc4,
                 const float* __restrict__ wc5, const float* __restrict__ bc5,
                 float* __restrict__ out)
{
    __shared__ __align__(16) float pool_s[256];    // [4][64]
    __shared__ __align__(16) float feats[1024];    // [4][256]
    __shared__ __align__(16) float h1[800];        // [4][200]
    __shared__ __align__(16) float h2[600];        // [4][150]
    __shared__ __align__(16) float h3[400];        // [4][100]
    __shared__ __align__(16) float h4[200];        // [4][50]
    __shared__ float zbuf[4];
    __shared__ float csc[56], css[56];

    const int tid  = threadIdx.x;
    const int blk  = blockIdx.x;
    const int lane = tid & 63;
    const int wv   = tid >> 6;

    pool_s[tid] = poolin[(size_t)blk * 256 + tid];
    if (tid < 56) {
        float th = qw[tid] * 0.5f;
        csc[tid] = cosf(th);
        css[tid] = sinf(th);
    }
    __syncthreads();

    // ---- fc: thread t owns feature t for all 4 elements ----
    {
        float acc[4];
        const float bv = bf[tid];
        #pragma unroll
        for (int e = 0; e < 4; e++) acc[e] = bv;
        const float4* wr = (const float4*)(wf + tid * 64);
        #pragma unroll
        for (int kc = 0; kc < 4; kc++) {
            float4 w0 = wr[kc * 4 + 0], w1_ = wr[kc * 4 + 1], w2_ = wr[kc * 4 + 2], w3_ = wr[kc * 4 + 3];
            #pragma unroll
            for (int e = 0; e < 4; e++) {
                const float4* pp = (const float4*)(pool_s + e * 64 + kc * 16);
                float4 p0 = pp[0], p1 = pp[1], p2 = pp[2], p3 = pp[3];
                float a = acc[e];
                a = fmaf(w0.x, p0.x, a); a = fmaf(w0.y, p0.y, a); a = fmaf(w0.z, p0.z, a); a = fmaf(w0.w, p0.w, a);
                a = fmaf(w1_.x, p1.x, a); a = fmaf(w1_.y, p1.y, a); a = fmaf(w1_.z, p1.z, a); a = fmaf(w1_.w, p1.w, a);
                a = fmaf(w2_.x, p2.x, a); a = fmaf(w2_.y, p2.y, a); a = fmaf(w2_.z, p2.z, a); a = fmaf(w2_.w, p2.w, a);
                a = fmaf(w3_.x, p3.x, a); a = fmaf(w3_.y, p3.y, a); a = fmaf(w3_.z, p3.z, a); a = fmaf(w3_.w, p3.w, a);
                acc[e] = a;
            }
        }
        #pragma unroll
        for (int e = 0; e < 4; e++) feats[e * 256 + tid] = fmaxf(acc[e], 0.f);
    }
    __syncthreads();

    // ---- quantum: wave wv handles element wv; amp idx = j*64 + lane ----
    {
        const float* base = feats + wv * 256;
        float v0 = base[lane], v1 = base[64 + lane];
        float v2 = base[128 + lane], v3 = base[192 + lane];
        float ssq = v0 * v0 + v1 * v1 + v2 * v2 + v3 * v3;
        #pragma unroll
        for (int off = 1; off < 64; off <<= 1) ssq += __shfl_xor(ssq, off, 64);
        const float inv = 1.0f / fmaxf(sqrtf(ssq), 1e-12f);
        v0 *= inv; v1 *= inv; v2 *= inv; v3 *= inv;

        for (int l = 0; l < 7; l++) {
            {   // RY q=0 (j bit1) then q=1 (j bit0)
                float c = csc[l * 8 + 0], s = css[l * 8 + 0];
                float n0 = c * v0 - s * v2, n2 = s * v0 + c * v2;
                float n1 = c * v1 - s * v3, n3 = s * v1 + c * v3;
                float c1 = csc[l * 8 + 1], s1 = css[l * 8 + 1];
                v0 = c1 * n0 - s1 * n1; v1 = s1 * n0 + c1 * n1;
                v2 = c1 * n2 - s1 * n3; v3 = s1 * n2 + c1 * n3;
            }
            #pragma unroll
            for (int q = 2; q < 8; q++) {   // RY on lane bits 5..0
                const int m = 1 << (7 - q);
                const float c = csc[l * 8 + q], s = css[l * 8 + q];
                const float sgn = (lane & m) ? s : -s;
                float t0 = __shfl_xor(v0, m, 64);
                float t1 = __shfl_xor(v1, m, 64);
                float t2 = __shfl_xor(v2, m, 64);
                float t3 = __shfl_xor(v3, m, 64);
                v0 = fmaf(sgn, t0, c * v0);
                v1 = fmaf(sgn, t1, c * v1);
                v2 = fmaf(sgn, t2, c * v2);
                v3 = fmaf(sgn, t3, c * v3);
            }
            // CNOT chain
            { float t = v2; v2 = v3; v3 = t; }
            v1 = __shfl_xor(v1, 32, 64);
            v3 = __shfl_xor(v3, 32, 64);
            #pragma unroll
            for (int q = 2; q < 7; q++) {
                const int mc = 1 << (7 - q), mt = 1 << (6 - q);
                float t0 = __shfl_xor(v0, mt, 64);
                float t1 = __shfl_xor(v1, mt, 64);
                float t2 = __shfl_xor(v2, mt, 64);
                float t3 = __shfl_xor(v3, mt, 64);
                if (lane & mc) { v0 = t0; v1 = t1; v2 = t2; v3 = t3; }
            }
        }
        float m0 = v0 * v0 + v1 * v1 - v2 * v2 - v3 * v3;
        #pragma unroll
        for (int off = 1; off < 64; off <<= 1) m0 += __shfl_xor(m0, off, 64);
        if (lane == 0) zbuf[wv] = m0;
    }
    __syncthreads();

    // ---- classifier MLP, weights in registers reused across 4 elements ----
    if (tid < 200) {
        const float w = wc1[tid], bv = bc1[tid];
        #pragma unroll
        for (int e = 0; e < 4; e++) h1[e * 200 + tid] = fmaxf(fmaf(zbuf[e], w, bv), 0.f);
    }
    __syncthreads();
    if (tid < 150) {
        float acc[4];
        const float bv = bc2[tid];
        #pragma unroll
        for (int e = 0; e < 4; e++) acc[e] = bv;
        const float4* wr = (const float4*)(wc2 + tid * 200);
        for (int kc = 0; kc < 25; kc++) {
            float4 wa = wr[2 * kc], wb = wr[2 * kc + 1];
            #pragma unroll
            for (int e = 0; e < 4; e++) {
                const float4* hp = (const float4*)(h1 + e * 200) + 2 * kc;
                float4 ha = hp[0], hb = hp[1];
                float a = acc[e];
                a = fmaf(wa.x, ha.x, a); a = fmaf(wa.y, ha.y, a); a = fmaf(wa.z, ha.z, a); a = fmaf(wa.w, ha.w, a);
                a = fmaf(wb.x, hb.x, a); a = fmaf(wb.y, hb.y, a); a = fmaf(wb.z, hb.z, a); a = fmaf(wb.w, hb.w, a);
                acc[e] = a;
            }
        }
        #pragma unroll
        for (int e = 0; e < 4; e++) h2[e * 150 + tid] = fmaxf(acc[e], 0.f);
    }
    __syncthreads();
    if (tid < 100) {
        float acc[4];
        const float bv = bc3[tid];
        #pragma unroll
        for (int e = 0; e < 4; e++) acc[e] = bv;
        const float2* wr = (const float2*)(wc3 + tid * 150);
        for (int k = 0; k < 75; k++) {
            float2 wa = wr[k];
            #pragma unroll
            for (int e = 0; e < 4; e++) {
                float2 hv = ((const float2*)(h2 + e * 150))[k];
                acc[e] = fmaf(wa.x, hv.x, fmaf(wa.y, hv.y, acc[e]));
            }
        }
        #pragma unroll
        for (int e = 0; e < 4; e++) h3[e * 100 + tid] = fmaxf(acc[e], 0.f);
    }
    __syncthreads();
    if (tid < 50) {
        float acc[4];
        const float bv = bc4[tid];
        #pragma unroll
        for (int e = 0; e < 4; e++) acc[e] = bv;
        const float4* wr = (const float4*)(wc4 + tid * 100);
        for (int kc = 0; kc < 25; kc++) {
            float4 wa = wr[kc];
            #pragma unroll
            for (int e = 0; e < 4; e++) {
                float4 hv = ((const float4*)(h3 + e * 100))[kc];
                float a = acc[e];
                a = fmaf(wa.x, hv.x, a); a = fmaf(wa.y, hv.y, a);
                a = fmaf(wa.z, hv.z, a); a = fmaf(wa.w, hv.w, a);
                acc[e] = a;
            }
        }
        #pragma unroll
        for (int e = 0; e < 4; e++) h4[e * 50 + tid] = fmaxf(acc[e], 0.f);
    }
    __syncthreads();
    if (tid < 4) {
        float acc = bc5[0];
        const float2* wr = (const float2*)wc5;
        #pragma unroll
        for (int k = 0; k < 25; k++) {
            float2 wa = wr[k];
            float2 hv = ((const float2*)(h4 + tid * 50))[k];
            acc = fmaf(wa.x, hv.x, fmaf(wa.y, hv.y, acc));
        }
        out[blk * 4 + tid] = 1.0f / (1.0f + expf(-acc));
    }
}

extern "C" void kernel_launch(void* const* d_in, const int* in_sizes, int n_in,
                              void* d_out, int out_size, void* d_ws, size_t ws_size,
                              hipStream_t stream) {
    const float* x   = (const float*)d_in[0];
    const float* w1  = (const float*)d_in[1];
    const float* b1  = (const float*)d_in[2];
    const float* w2  = (const float*)d_in[3];
    const float* b2  = (const float*)d_in[4];
    const float* w3  = (const float*)d_in[5];
    const float* b3  = (const float*)d_in[6];
    const float* wf  = (const float*)d_in[7];
    const float* bf  = (const float*)d_in[8];
    const float* qw  = (const float*)d_in[9];
    const float* wc1 = (const float*)d_in[10];
    const float* bc1 = (const float*)d_in[11];
    const float* wc2 = (const float*)d_in[12];
    const float* bc2 = (const float*)d_in[13];
    const float* wc3 = (const float*)d_in[14];
    const float* bc3 = (const float*)d_in[15];
    const float* wc4 = (const float*)d_in[16];
    const float* bc4 = (const float*)d_in[17];
    const float* wc5 = (const float*)d_in[18];
    const float* bc5 = (const float*)d_in[19];
    float* out = (float*)d_out;

    float* poolbuf = (float*)d_ws;   // 4096*64 floats = 1 MB

    convpool_kernel<<<4096, 256, 0, stream>>>(x, w1, b1, w2, b2, w3, b3, poolbuf);
    head_kernel<<<1024, 256, 0, stream>>>(poolbuf, wf, bf, qw,
                                          wc1, bc1, wc2, bc2, wc3, bc3,
                                          wc4, bc4, wc5, bc5, out);
}